// Round 2
// baseline (337.334 us; speedup 1.0000x reference)
//
#include <hip/hip_runtime.h>
#include <hip/hip_fp16.h>
#include <hip/hip_cooperative_groups.h>

namespace cg = cooperative_groups;

// Problem constants (from reference).
#define N_GENOMES 30000
#define N_GENES   240000
#define N_SAMPLES 128
#define N_SEQS    80000
#define CAP       32   // max genes per seq (Poisson mean 3; P(overflow) ~ 3e-17)

// Native vector types for __builtin_nontemporal_load/store.
typedef float        f32x4 __attribute__((ext_vector_type(4)));
typedef unsigned int u32x4 __attribute__((ext_vector_type(4)));

#define LOG2E 1.4426950408889634f

#if __has_builtin(__builtin_amdgcn_exp2f)
#define EXP2F(x) __builtin_amdgcn_exp2f(x)
#else
#define EXP2F(x) exp2f(x)
#endif

// ---------------------------------------------------------------------------
// Single fused cooperative kernel. Replaces memset + prep + accum (3
// dispatches with inter-kernel L2 flushes) with 1 dispatch + 2 grid.sync().
//
// Phase 0: zero cnt (was a hipMemsetAsync dispatch).
// Phase 1a: bucket-scatter genes by seq id, PACKED 4B records:
//   genome (15 bits) | pos quantized to 17 bits. Slots 0..3 -> DENSE
//   bucket0 [N_SEQS][4] (16B rows); slots 4..31 -> bucketOv [N_SEQS][28].
//   Neither pre-zeroed; accum masks dead slots by count.
// Phase 1b: XCD-LOCAL compress. Block b (qg = b%8) writes ONLY AB16 slice
//   qg: AB16T[qg][genome][qw], qw = quad&3, reading A/B at 64B granularity
//   (2x line amplification, L3-absorbed). The slice (1.92 MB) is written
//   dirty into the SAME XCD L2 that phase 2 gathers from -- no inter-kernel
//   flush evicts it (grid.sync is a fence, not a cache wipe).
// Phase 2: accum. qg = b%8 (XCD-sharded gather), block owns a CONTIGUOUS
//   ~625-seq chunk so out NT-stores sweep 320KB sequentially per block.
//   (a+1) and log2(e) are folded into AB16 -> exp is a single v_exp_f32.
// ---------------------------------------------------------------------------
__global__ __launch_bounds__(256, 4) void fused_kernel(
    const float* __restrict__ A,
    const float* __restrict__ B,
    const float* __restrict__ pos,
    const int*   __restrict__ genome_idx,
    const int*   __restrict__ seq_idx,
    int*          __restrict__ cnt,      // N_SEQS
    unsigned int* __restrict__ bucket0,  // N_SEQS*4 packed records (uninit)
    unsigned int* __restrict__ bucketOv, // N_SEQS*28 packed records (uninit)
    float4*       __restrict__ AB16,     // 8 x 30000 x 4 float4, qg-major
    float*        __restrict__ out)
{
    cg::grid_group grid = cg::this_grid();

    const int b    = blockIdx.x;
    const int tid  = threadIdx.x;
    const int gtid = b * 256 + tid;
    const int GS   = gridDim.x << 8;      // total threads
    const int qg   = b & 7;               // -> XCD under round-robin dispatch
    const int bg   = b >> 3;              // block index within qg shard
    const int bgCount = gridDim.x >> 3;

    // ---- Phase 0: zero cnt --------------------------------------------
    for (int i = gtid; i < N_SEQS; i += GS) cnt[i] = 0;
    grid.sync();

    // ---- Phase 1a: scatter --------------------------------------------
    for (int gene = gtid; gene < N_GENES; gene += GS) {
        int   s = seq_idx[gene];
        int   g = genome_idx[gene];
        float p = pos[gene];
        unsigned int q   = (unsigned int)(p * 131072.0f);   // exact mul, trunc
        unsigned int rec = (unsigned int)g | (q << 15);
        int slot = atomicAdd(&cnt[s], 1);
        if (slot < 4)        bucket0[s * 4 + slot] = rec;
        else if (slot < CAP) bucketOv[s * 28 + (slot - 4)] = rec;
    }

    // ---- Phase 1b: XCD-local compress (slice qg only) -----------------
    // Thread handles one genome: reads A/B floats [qg*16, qg*16+16) of the
    // 128-float row (64B contiguous), writes 64B contiguous into slice qg.
    {
        const int sliceThreads = bgCount << 8;
        for (int genome = bg * 256 + tid; genome < N_GENOMES; genome += sliceThreads) {
            const f32x4* Ar = (const f32x4*)(A + (size_t)genome * 128 + qg * 16);
            const f32x4* Br = (const f32x4*)(B + (size_t)genome * 128 + qg * 16);
            float4* dst = AB16 + ((size_t)qg * N_GENOMES + genome) * 4;
            #pragma unroll
            for (int qw = 0; qw < 4; ++qw) {
                f32x4 a  = __builtin_nontemporal_load(Ar + qw);  // read-once: keep L2 clean
                f32x4 bb = __builtin_nontemporal_load(Br + qw);
                __half2 h[4];
                h[0] = __floats2half2_rn((a.x + 1.0f) * LOG2E, (a.y + 1.0f) * LOG2E);
                h[1] = __floats2half2_rn((a.z + 1.0f) * LOG2E, (a.w + 1.0f) * LOG2E);
                h[2] = __floats2half2_rn(bb.x * LOG2E, bb.y * LOG2E);
                h[3] = __floats2half2_rn(bb.z * LOG2E, bb.w * LOG2E);
                dst[qw] = *reinterpret_cast<float4*>(h);   // cached: phase 2 re-reads from this XCD's L2
            }
        }
    }

    grid.sync();

    // ---- Phase 2: accum ------------------------------------------------
    {
        const int per  = (N_SEQS + bgCount - 1) / bgCount;   // 625 @ 128 bgs
        const int seq0 = bg * per;
        const int send = (seq0 + per < N_SEQS) ? seq0 + per : N_SEQS;
        const int qw   = tid & 3;
        // This XCD's slice base, offset by this thread's qw.
        const float4* T = AB16 + (size_t)qg * N_GENOMES * 4 + qw;

        for (int seq = seq0 + (tid >> 2); seq < send; seq += 64) {
            // Dense 16B chunk-0 row; issued immediately, independent of cnt.
            u32x4 r4 = reinterpret_cast<const u32x4*>(bucket0)[seq];
            int   n  = cnt[seq];                    // issued in parallel with r4
            if (n > CAP) n = CAP;

            float4 acc = make_float4(0.f, 0.f, 0.f, 0.f);

            // Chunk 0 (covers n<=4: the vast majority of non-empty seqs).
            {
                unsigned int r[4] = { r4.x, r4.y, r4.z, r4.w };
                float4 raw[4];
                #pragma unroll
                for (int j = 0; j < 4; ++j) {
                    unsigned int g = (j < n) ? (r[j] & 0x7fffu) : 0u;  // dead -> row 0 (hot)
                    raw[j] = T[(size_t)g * 4];
                }
                #pragma unroll
                for (int j = 0; j < 4; ++j) {
                    float p = (float)(r[j] >> 15) * (1.0f / 131072.0f);
                    const __half2* hp = reinterpret_cast<const __half2*>(&raw[j]);
                    float2 a01 = __half22float2(hp[0]);
                    float2 a23 = __half22float2(hp[1]);
                    float2 b01 = __half22float2(hp[2]);
                    float2 b23 = __half22float2(hp[3]);
                    if (j < n) {                       // (a+1), log2e folded into AB16
                        acc.x += EXP2F(a01.x - p * b01.x);
                        acc.y += EXP2F(a01.y - p * b01.y);
                        acc.z += EXP2F(a23.x - p * b23.x);
                        acc.w += EXP2F(a23.y - p * b23.y);
                    }
                }
            }

            // Rare tail: n > 4 (P ~ 18%), chunks of 4 from the spill array.
            if (n > 4) {
                const u32x4* bkv =
                    reinterpret_cast<const u32x4*>(bucketOv + (size_t)seq * 28);
                for (int i0 = 4; i0 < n; i0 += 4) {
                    u32x4 t4 = bkv[(i0 - 4) >> 2];
                    unsigned int r[4] = { t4.x, t4.y, t4.z, t4.w };
                    float4 raw[4];
                    #pragma unroll
                    for (int j = 0; j < 4; ++j) {
                        unsigned int g = (i0 + j < n) ? (r[j] & 0x7fffu) : 0u;
                        raw[j] = T[(size_t)g * 4];
                    }
                    #pragma unroll
                    for (int j = 0; j < 4; ++j) {
                        float p = (float)(r[j] >> 15) * (1.0f / 131072.0f);
                        const __half2* hp = reinterpret_cast<const __half2*>(&raw[j]);
                        float2 a01 = __half22float2(hp[0]);
                        float2 a23 = __half22float2(hp[1]);
                        float2 b01 = __half22float2(hp[2]);
                        float2 b23 = __half22float2(hp[3]);
                        if (i0 + j < n) {
                            acc.x += EXP2F(a01.x - p * b01.x);
                            acc.y += EXP2F(a01.y - p * b01.y);
                            acc.z += EXP2F(a23.x - p * b23.x);
                            acc.w += EXP2F(a23.y - p * b23.y);
                        }
                    }
                }
            }

            // Out is written once and never re-read -> nontemporal.
            f32x4 o = { acc.x, acc.y, acc.z, acc.w };
            __builtin_nontemporal_store(o, (f32x4*)out + (size_t)seq * 32 + (qg << 2) + qw);
        }
    }
}

extern "C" void kernel_launch(void* const* d_in, const int* in_sizes, int n_in,
                              void* d_out, int out_size, void* d_ws, size_t ws_size,
                              hipStream_t stream) {
    const float* A    = (const float*)d_in[0];
    const float* B    = (const float*)d_in[1];
    const float* pos  = (const float*)d_in[2];
    const int*   gidx = (const int*)d_in[3];
    const int*   sidx = (const int*)d_in[4];
    float*       out  = (float*)d_out;

    // Workspace layout (256 MiB available, ~25.9 MB used):
    //   [0, 15,360,000)              AB16T: 8 x 30000 x 4 float4, qg-major
    //   [15,360,000, 15,680,000)     cnt: N_SEQS ints
    //   [15,680,000, 16,960,000)     bucket0: N_SEQS*4 uints (dense 16B rows)
    //   [16,960,000, 25,920,000)     bucketOv: N_SEQS*28 uints (spill)
    char*         ws       = (char*)d_ws;
    float4*       AB16     = (float4*)ws;
    int*          cnt      = (int*)(ws + (size_t)N_GENOMES * 32 * 16);
    unsigned int* bucket0  = (unsigned int*)(cnt + N_SEQS);
    unsigned int* bucketOv = bucket0 + (size_t)N_SEQS * 4;

    // Cooperative grid: 1024 blocks = 4 blocks/CU x 256 CUs.
    // __launch_bounds__(256,4) caps VGPR<=128 so 4 blocks/CU co-reside.
    // Clamp by occupancy anyway (multiple of 8 for the qg->XCD mapping).
    int blocksPerCU = 0;
    (void)hipOccupancyMaxActiveBlocksPerMultiprocessor(
        &blocksPerCU, (const void*)fused_kernel, 256, 0);
    int nblk = blocksPerCU * 256;
    if (nblk > 1024) nblk = 1024;
    nblk &= ~7;                 // multiple of 8
    if (nblk < 8) nblk = 8;     // degenerate fallback (still correct)

    void* args[] = { (void*)&A, (void*)&B, (void*)&pos, (void*)&gidx, (void*)&sidx,
                     (void*)&cnt, (void*)&bucket0, (void*)&bucketOv,
                     (void*)&AB16, (void*)&out };
    (void)hipLaunchCooperativeKernel((const void*)fused_kernel,
                                     dim3(nblk), dim3(256), args, 0, stream);
}

// Round 3
// 285.872 us; speedup vs baseline: 1.1800x; 1.1800x over previous
//
#include <hip/hip_runtime.h>

// Problem constants (from reference).
#define N_GENOMES 30000
#define N_GENES   240000
#define N_SAMPLES 128
#define N_SEQS    80000

#define LOG2E 1.4426950408889634f

#if __has_builtin(__builtin_amdgcn_exp2f)
#define EXP2F(x) __builtin_amdgcn_exp2f(x)
#else
#define EXP2F(x) exp2f(x)
#endif

// ---------------------------------------------------------------------------
// Gene-direct kernel. Replaces the whole memset+scatter+compress+accum
// pipeline (3 dispatches, ~46 MB of AB16 intermediate traffic, bucket/cnt
// arrays) with ONE pass over genes + fp32 atomics into out.
//
// Structure: one wave per gene (4 genes in flight per 256-thread block).
//   lane l owns samples 2l, 2l+1 (float2 = 8B/lane -> 512B per wave load).
//   out[seq] += exp2((a+1)*log2e - (p*log2e)*b)  -- exact same math as the
//   reference, in fp32 end-to-end (absmax should drop from 8.0 to ~1e-3).
//
// Why this is fast:
//   - genome_idx is SORTED: ~8 consecutive genes share a genome row, so A/B
//     row reads are L1/L2-hot. Blocks are mapped chunked-by-XCD
//     (blockIdx%8 = XCD, each XCD owns a contiguous 30000-gene range), so
//     each XCD's A/B working set is ~3.8 MB -> resident in its 4 MiB L2.
//   - a wave's 128 atomicAdds are CONTIGUOUS (512B = 4 lines): they coalesce
//     into line-level L2 RMWs, store-like cost. Seq collisions are rare
//     (mean 3 genes per seq across 80K rows) -> negligible contention.
//   - atomics are fire-and-forget (no return value), so the per-gene loop
//     has no dependent-load chain to stall on; 8192 independent waves.
// out must be pre-zeroed (done by hipMemsetAsync below); seqs with zero
// genes correctly stay 0.
// ---------------------------------------------------------------------------
#define GENES_PER_XCD (N_GENES / 8)     // 30000
#define BLOCKS_PER_XCD 256
#define GENES_PER_BLOCK 118             // 256*118 = 30208 >= 30000

__global__ __launch_bounds__(256) void gene_kernel(
    const float* __restrict__ A,
    const float* __restrict__ B,
    const float* __restrict__ pos,
    const int*   __restrict__ genome_idx,
    const int*   __restrict__ seq_idx,
    float*       __restrict__ out)
{
    const int lane = threadIdx.x & 63;
    const int wav  = threadIdx.x >> 6;             // 0..3
    const int xcd  = blockIdx.x & 7;               // -> XCD under round-robin
    const int jb   = blockIdx.x >> 3;              // 0..255 within shard

    const int gbase = xcd * GENES_PER_XCD + jb * GENES_PER_BLOCK;
    const int glim  = (xcd + 1) * GENES_PER_XCD;
    int gend = gbase + GENES_PER_BLOCK;
    if (gend > glim) gend = glim;

    for (int g = gbase + wav; g < gend; g += 4) {
        int   gm = genome_idx[g];                  // wave-uniform
        int   s  = seq_idx[g];                     // wave-uniform
        float pl = pos[g] * LOG2E;                 // wave-uniform

        const float2* Ar = (const float2*)(A + (size_t)gm * N_SAMPLES);
        const float2* Br = (const float2*)(B + (size_t)gm * N_SAMPLES);
        float2 a = Ar[lane];                       // 512B coalesced per wave
        float2 b = Br[lane];

        // (a + 1 - p*b) * log2e, folded: fma(b, -p*log2e, fma(a, L, L))
        float x0 = fmaf(b.x, -pl, fmaf(a.x, LOG2E, LOG2E));
        float x1 = fmaf(b.y, -pl, fmaf(a.y, LOG2E, LOG2E));
        float e0 = EXP2F(x0);
        float e1 = EXP2F(x1);

        float* o = out + (size_t)s * N_SAMPLES + lane * 2;
        atomicAdd(o,     e0);                      // contiguous 512B per wave:
        atomicAdd(o + 1, e1);                      // line-coalesced L2 RMWs
    }
}

extern "C" void kernel_launch(void* const* d_in, const int* in_sizes, int n_in,
                              void* d_out, int out_size, void* d_ws, size_t ws_size,
                              hipStream_t stream) {
    const float* A    = (const float*)d_in[0];
    const float* B    = (const float*)d_in[1];
    const float* pos  = (const float*)d_in[2];
    const int*   gidx = (const int*)d_in[3];
    const int*   sidx = (const int*)d_in[4];
    float*       out  = (float*)d_out;

    // out must start at zero (it is the accumulator; empty seqs stay 0).
    hipMemsetAsync(out, 0, (size_t)N_SEQS * N_SAMPLES * sizeof(float), stream);

    // 2048 blocks: 256 per XCD shard (blockIdx%8 = XCD), 8 blocks/CU.
    gene_kernel<<<8 * BLOCKS_PER_XCD, 256, 0, stream>>>(
        A, B, pos, gidx, sidx, out);
}

// Round 4
// 135.062 us; speedup vs baseline: 2.4976x; 2.1166x over previous
//
#include <hip/hip_runtime.h>
#include <hip/hip_fp16.h>

// Problem constants (from reference).
#define N_GENOMES 30000
#define N_GENES   240000
#define N_SAMPLES 128
#define N_SEQS    80000
#define CAP       32   // max genes per seq (Poisson mean 3; P(overflow) ~ 3e-17)

#define SCATTER_BLOCKS  ((N_GENES + 255) / 256)        // 938
#define COMPRESS_BLOCKS ((N_GENOMES * 32) / 256)       // 3750 (exact)

// Native vector types for __builtin_nontemporal_load/store.
typedef float        f32x4 __attribute__((ext_vector_type(4)));
typedef unsigned int u32x4 __attribute__((ext_vector_type(4)));

#define LOG2E 1.4426950408889634f

#if __has_builtin(__builtin_amdgcn_exp2f)
#define EXP2F(x) __builtin_amdgcn_exp2f(x)
#else
#define EXP2F(x) exp2f(x)
#endif

// ---------------------------------------------------------------------------
// Round-1 structure (best measured: 122.5us), tightened.
// Lessons baked in: NO fp32 atomics into out (round 3: memory-side RMW,
// 245MB writes at 1.2TB/s); NO cooperative fusion (round 2: grid cap kills
// TLP, 250us). Fixed harness overhead ~85us; variable part ~38us; traffic
// floor ~25us -- this round chases the ~13us of slack.
//
// prep (1 dispatch, two block roles):
//   scatter blocks: bucket-scatter genes by seq, PACKED 4B records
//     genome(15b) | pos*2^17(17b). Slots 0..3 -> DENSE bucket0[N_SEQS][4]
//     (16B rows); 4..31 -> bucketOv[N_SEQS][28]. Not pre-zeroed; accum
//     masks dead slots by count. NT stores: re-read only after the
//     dispatch-boundary flush, so L2-caching them buys nothing.
//   compress blocks: A/B -> fp16, (+1) and log2(e) folded in, qg-major
//     XCD-sharded layout AB16T[qg][genome][qw] (slice = 1.92MB, fits one
//     XCD's 4MiB L2). NT loads (read-once) and NT stores (cross-dispatch
//     re-read; keep prep's L2 clean for the A/B stream).
// accum: qg = b%8 -> XCD under round-robin dispatch; block covers 64
//   consecutive seqs x 4 qw lanes for its qg. NEW: slice warm-up -- each
//   block streams its 96-float4 share of the XCD slice (1250 blocks x 96
//   = 120000 = whole slice) with cached loads before the gather loop, so
//   random 64B first-touches become L2 hits; overlaps bucket-row latency.
// ---------------------------------------------------------------------------
__global__ __launch_bounds__(256) void prep_kernel(
    const float* __restrict__ A,
    const float* __restrict__ B,
    const float* __restrict__ pos,
    const int*   __restrict__ genome_idx,
    const int*   __restrict__ seq_idx,
    int*          __restrict__ cnt,      // N_SEQS, zeroed
    unsigned int* __restrict__ bucket0,  // N_SEQS*4 packed records (uninit)
    unsigned int* __restrict__ bucketOv, // N_SEQS*28 packed records (uninit)
    float4*       __restrict__ AB16)     // 8 x 30000 x 4 float4, qg-major
{
    int b = blockIdx.x;
    if (b < SCATTER_BLOCKS) {
        int gene = b * 256 + threadIdx.x;
        if (gene >= N_GENES) return;
        int   s = seq_idx[gene];
        int   g = genome_idx[gene];
        float p = pos[gene];
        unsigned int q   = (unsigned int)(p * 131072.0f);   // exact mul, trunc
        unsigned int rec = (unsigned int)g | (q << 15);
        int slot = atomicAdd(&cnt[s], 1);
        if (slot < 4)
            __builtin_nontemporal_store(rec, bucket0 + s * 4 + slot);
        else if (slot < CAP)
            __builtin_nontemporal_store(rec, bucketOv + s * 28 + (slot - 4));
    } else {
        int idx = (b - SCATTER_BLOCKS) * 256 + threadIdx.x; // genome*32+quad
        f32x4 a  = __builtin_nontemporal_load((const f32x4*)A + idx);
        f32x4 bb = __builtin_nontemporal_load((const f32x4*)B + idx);
        __half2 h[4];
        h[0] = __floats2half2_rn((a.x + 1.0f) * LOG2E, (a.y + 1.0f) * LOG2E);
        h[1] = __floats2half2_rn((a.z + 1.0f) * LOG2E, (a.w + 1.0f) * LOG2E);
        h[2] = __floats2half2_rn(bb.x * LOG2E, bb.y * LOG2E);
        h[3] = __floats2half2_rn(bb.z * LOG2E, bb.w * LOG2E);
        int genome = idx >> 5;
        int quad   = idx & 31;
        int qg = quad >> 2, qw = quad & 3;
        f32x4 hv = *reinterpret_cast<f32x4*>(h);
        __builtin_nontemporal_store(hv,
            (f32x4*)AB16 + ((size_t)qg * N_GENOMES + genome) * 4 + qw);
    }
}

__global__ __launch_bounds__(256) void accum_kernel(
    const float4*       __restrict__ AB16,
    const int*          __restrict__ cnt,
    const unsigned int* __restrict__ bucket0,
    const unsigned int* __restrict__ bucketOv,
    float*              __restrict__ out)
{
    int b   = blockIdx.x;
    int qg  = b & 7;
    int bg  = b >> 3;                       // 0..1249 within qg shard
    int tid = threadIdx.x;
    int seq = bg * 64 + (tid >> 2);         // grid exact: 1250*64 = 80000
    int qw  = tid & 3;

    // This XCD's slice base.
    const float4* slice = AB16 + (size_t)qg * N_GENOMES * 4;

    // ---- Slice warm-up: pull this block's 96-float4 share of the 1.92MB
    // slice into the local L2 with sequential cached loads. 1250 blocks/qg
    // x 96 = 120000 float4 = the whole slice. Issued before (and retired
    // in parallel with) the bucket-row load; sunk so it isn't DCE'd.
    if (tid < 96) {
        f32x4 w = ((const f32x4*)slice)[bg * 96 + tid];
        asm volatile("" :: "v"(w));         // keep the load; fills L2
    }

    // Dense 16B chunk-0 row; issued immediately, independent of cnt.
    u32x4 r4 = reinterpret_cast<const u32x4*>(bucket0)[seq];
    int   n  = cnt[seq];                    // issued in parallel with r4
    if (n > CAP) n = CAP;

    const float4* T = slice + qw;

    float4 acc = make_float4(0.f, 0.f, 0.f, 0.f);

    // Chunk 0 (covers n<=4: the vast majority of non-empty seqs).
    {
        unsigned int r[4] = { r4.x, r4.y, r4.z, r4.w };
        float4 raw[4];
        #pragma unroll
        for (int j = 0; j < 4; ++j) {
            unsigned int g = (j < n) ? (r[j] & 0x7fffu) : 0u;  // dead -> row 0 (hot)
            raw[j] = T[(size_t)g * 4];
        }
        #pragma unroll
        for (int j = 0; j < 4; ++j) {
            float p = (float)(r[j] >> 15) * (1.0f / 131072.0f);
            const __half2* hp = reinterpret_cast<const __half2*>(&raw[j]);
            float2 a01 = __half22float2(hp[0]);
            float2 a23 = __half22float2(hp[1]);
            float2 b01 = __half22float2(hp[2]);
            float2 b23 = __half22float2(hp[3]);
            if (j < n) {                       // (a+1), log2e folded into AB16
                acc.x += EXP2F(a01.x - p * b01.x);
                acc.y += EXP2F(a01.y - p * b01.y);
                acc.z += EXP2F(a23.x - p * b23.x);
                acc.w += EXP2F(a23.y - p * b23.y);
            }
        }
    }

    // Rare tail: n > 4 (P ~ 35%), chunks of 4 from the spill array.
    if (n > 4) {
        const u32x4* bkv =
            reinterpret_cast<const u32x4*>(bucketOv + (size_t)seq * 28); // 112B: 16B-aligned
        for (int i0 = 4; i0 < n; i0 += 4) {
            u32x4 t4 = bkv[(i0 - 4) >> 2];
            unsigned int r[4] = { t4.x, t4.y, t4.z, t4.w };
            float4 raw[4];
            #pragma unroll
            for (int j = 0; j < 4; ++j) {
                unsigned int g = (i0 + j < n) ? (r[j] & 0x7fffu) : 0u;
                raw[j] = T[(size_t)g * 4];
            }
            #pragma unroll
            for (int j = 0; j < 4; ++j) {
                float p = (float)(r[j] >> 15) * (1.0f / 131072.0f);
                const __half2* hp = reinterpret_cast<const __half2*>(&raw[j]);
                float2 a01 = __half22float2(hp[0]);
                float2 a23 = __half22float2(hp[1]);
                float2 b01 = __half22float2(hp[2]);
                float2 b23 = __half22float2(hp[3]);
                if (i0 + j < n) {
                    acc.x += EXP2F(a01.x - p * b01.x);
                    acc.y += EXP2F(a01.y - p * b01.y);
                    acc.z += EXP2F(a23.x - p * b23.x);
                    acc.w += EXP2F(a23.y - p * b23.y);
                }
            }
        }
    }

    // Out is written once and never re-read -> nontemporal. 64B-aligned
    // chunk per (seq,qg) = 2 full 32B sectors: no write amplification.
    f32x4 o = { acc.x, acc.y, acc.z, acc.w };
    __builtin_nontemporal_store(o, (f32x4*)out + (size_t)seq * 32 + (qg << 2) + qw);
}

extern "C" void kernel_launch(void* const* d_in, const int* in_sizes, int n_in,
                              void* d_out, int out_size, void* d_ws, size_t ws_size,
                              hipStream_t stream) {
    const float* A    = (const float*)d_in[0];
    const float* B    = (const float*)d_in[1];
    const float* pos  = (const float*)d_in[2];
    const int*   gidx = (const int*)d_in[3];
    const int*   sidx = (const int*)d_in[4];
    float*       out  = (float*)d_out;

    // Workspace layout (256 MiB available, ~25.9 MB used):
    //   [0, 15,360,000)              AB16T: 8 x 30000 x 4 float4, qg-major
    //   [15,360,000, 15,680,000)     cnt: N_SEQS ints
    //   [15,680,000, 16,960,000)     bucket0: N_SEQS*4 uints (dense 16B rows)
    //   [16,960,000, 25,920,000)     bucketOv: N_SEQS*28 uints (spill)
    char*         ws       = (char*)d_ws;
    float4*       AB16     = (float4*)ws;
    int*          cnt      = (int*)(ws + (size_t)N_GENOMES * 32 * 16);
    unsigned int* bucket0  = (unsigned int*)(cnt + N_SEQS);
    unsigned int* bucketOv = bucket0 + (size_t)N_SEQS * 4;

    // Zero ONLY cnt (320 KB): bucket dead slots are masked by count in accum.
    hipMemsetAsync(cnt, 0, N_SEQS * sizeof(int), stream);

    prep_kernel<<<SCATTER_BLOCKS + COMPRESS_BLOCKS, 256, 0, stream>>>(
        A, B, pos, gidx, sidx, cnt, bucket0, bucketOv, AB16);

    // 8 qg-shards x 1250 seq-blocks; blockIdx%8 = qg -> XCD under
    // round-robin dispatch (bijective: 10000 % 8 == 0).
    accum_kernel<<<(N_SEQS / 64) * 8, 256, 0, stream>>>(
        AB16, cnt, bucket0, bucketOv, out);
}

// Round 5
// 122.277 us; speedup vs baseline: 2.7588x; 1.1046x over previous
//
#include <hip/hip_runtime.h>
#include <hip/hip_fp16.h>

// Problem constants (from reference).
#define N_GENOMES 30000
#define N_GENES   240000
#define N_SAMPLES 128
#define N_SEQS    80000
#define CAP       32   // max genes per seq (Poisson mean 3; P(overflow) ~ 3e-17)

#define SCATTER_BLOCKS  ((N_GENES + 255) / 256)        // 938
#define COMPRESS_BLOCKS ((N_GENOMES * 32) / 256)       // 3750 (exact)

// Native vector types for __builtin_nontemporal_load/store.
typedef float        f32x4 __attribute__((ext_vector_type(4)));
typedef unsigned int u32x4 __attribute__((ext_vector_type(4)));

#define LOG2E 1.4426950408889634f

#if __has_builtin(__builtin_amdgcn_exp2f)
#define EXP2F(x) __builtin_amdgcn_exp2f(x)
#else
#define EXP2F(x) exp2f(x)
#endif

// ---------------------------------------------------------------------------
// ROUND-1 STRUCTURE RESTORED (best measured: 122.5us). Session ledger:
//   r2 cooperative fusion:      337us (grid cap kills TLP; coop launch
//                                breaks graph capture -> +87us overhead)
//   r3 direct fp32 atomics:     286us (non-coherent XCD L2s -> memory-side
//                                RMW, 246MB writes at 1.2TB/s)
//   r4 NT bucket/AB16 stores:   135us (scattered 4B NT stores = 32B-sector
//                                amplification; NT defeats L2 write-merging.
//                                NT stores are for STREAMING patterns only)
//   r4 accum slice warm-up:     confounded with above; double-fetch risk.
// Budget: ~85us fixed (harness 256MiB workspace re-poison fill ~45us +
// launch gaps) + ~35us variable vs ~25us traffic floor.
//
// prep (1 dispatch, two block roles):
//   scatter blocks: bucket-scatter genes by seq, PACKED 4B records
//     genome(15b) | pos*2^17(17b). Slots 0..3 -> DENSE bucket0[N_SEQS][4]
//     (16B rows); 4..31 -> bucketOv[N_SEQS][28]. Not pre-zeroed; accum
//     masks dead slots by count. PLAIN cached stores: L2 write-allocate
//     merges neighboring 4B records into full lines (r4 lesson).
//     NT loads on the three input streams (read-once) -- no store-side
//     hazard; keeps them from evicting bucket write-combining lines.
//   compress blocks: A/B -> fp16, (+1) and log2(e) folded in, qg-major
//     XCD-sharded layout AB16T[qg][genome][qw]; slice = 1.92MB fits one
//     XCD's 4MiB L2. NT loads (read-once); PLAIN stores (64B-merged in L2).
// accum: qg = b%8 -> XCD under round-robin dispatch; block covers 64
//   consecutive seqs x 4 qw lanes of its qg slice; out NT-stores sweep
//   sequentially. Every out element is written (n==0 -> zeros): no out
//   memset needed.
// ---------------------------------------------------------------------------
__global__ __launch_bounds__(256) void prep_kernel(
    const float* __restrict__ A,
    const float* __restrict__ B,
    const float* __restrict__ pos,
    const int*   __restrict__ genome_idx,
    const int*   __restrict__ seq_idx,
    int*          __restrict__ cnt,      // N_SEQS, zeroed
    unsigned int* __restrict__ bucket0,  // N_SEQS*4 packed records (uninit)
    unsigned int* __restrict__ bucketOv, // N_SEQS*28 packed records (uninit)
    float4*       __restrict__ AB16)     // 8 x 30000 x 4 float4, qg-major
{
    int b = blockIdx.x;
    if (b < SCATTER_BLOCKS) {
        int gene = b * 256 + threadIdx.x;
        if (gene >= N_GENES) return;
        int   s = __builtin_nontemporal_load(seq_idx + gene);
        int   g = __builtin_nontemporal_load(genome_idx + gene);
        float p = __builtin_nontemporal_load(pos + gene);
        unsigned int q   = (unsigned int)(p * 131072.0f);   // exact mul, trunc
        unsigned int rec = (unsigned int)g | (q << 15);
        int slot = atomicAdd(&cnt[s], 1);
        if (slot < 4)        bucket0[s * 4 + slot] = rec;          // cached:
        else if (slot < CAP) bucketOv[s * 28 + (slot - 4)] = rec;  // L2-merged
    } else {
        int idx = (b - SCATTER_BLOCKS) * 256 + threadIdx.x; // genome*32+quad
        f32x4 a  = __builtin_nontemporal_load((const f32x4*)A + idx);
        f32x4 bb = __builtin_nontemporal_load((const f32x4*)B + idx);
        __half2 h[4];
        h[0] = __floats2half2_rn((a.x + 1.0f) * LOG2E, (a.y + 1.0f) * LOG2E);
        h[1] = __floats2half2_rn((a.z + 1.0f) * LOG2E, (a.w + 1.0f) * LOG2E);
        h[2] = __floats2half2_rn(bb.x * LOG2E, bb.y * LOG2E);
        h[3] = __floats2half2_rn(bb.z * LOG2E, bb.w * LOG2E);
        int genome = idx >> 5;
        int quad   = idx & 31;
        int qg = quad >> 2, qw = quad & 3;
        // qg-major sharded layout; PLAIN store (r4: NT here regressed).
        AB16[((size_t)qg * N_GENOMES + genome) * 4 + qw] =
            *reinterpret_cast<float4*>(h);
    }
}

__global__ __launch_bounds__(256) void accum_kernel(
    const float4*       __restrict__ AB16,
    const int*          __restrict__ cnt,
    const unsigned int* __restrict__ bucket0,
    const unsigned int* __restrict__ bucketOv,
    float*              __restrict__ out)
{
    int b   = blockIdx.x;
    int qg  = b & 7;
    int tid = threadIdx.x;
    int seq = (b >> 3) * 64 + (tid >> 2);   // grid exact: 1250*64 = 80000
    int qw  = tid & 3;

    // Dense 16B chunk-0 row; issued immediately, independent of cnt.
    u32x4 r4 = reinterpret_cast<const u32x4*>(bucket0)[seq];
    int   n  = cnt[seq];                    // issued in parallel with r4
    if (n > CAP) n = CAP;

    // This XCD's slice base, offset by this thread's qw.
    const float4* T = AB16 + (size_t)qg * N_GENOMES * 4 + qw;

    float4 acc = make_float4(0.f, 0.f, 0.f, 0.f);

    // Chunk 0 (covers n<=4: 81.5% of seqs at Poisson mean 3).
    {
        unsigned int r[4] = { r4.x, r4.y, r4.z, r4.w };
        float4 raw[4];
        #pragma unroll
        for (int j = 0; j < 4; ++j) {
            unsigned int g = (j < n) ? (r[j] & 0x7fffu) : 0u;  // dead -> row 0 (hot)
            raw[j] = T[(size_t)g * 4];
        }
        #pragma unroll
        for (int j = 0; j < 4; ++j) {
            float p = (float)(r[j] >> 15) * (1.0f / 131072.0f);
            const __half2* hp = reinterpret_cast<const __half2*>(&raw[j]);
            float2 a01 = __half22float2(hp[0]);
            float2 a23 = __half22float2(hp[1]);
            float2 b01 = __half22float2(hp[2]);
            float2 b23 = __half22float2(hp[3]);
            if (j < n) {                       // (a+1), log2e folded into AB16
                acc.x += EXP2F(a01.x - p * b01.x);
                acc.y += EXP2F(a01.y - p * b01.y);
                acc.z += EXP2F(a23.x - p * b23.x);
                acc.w += EXP2F(a23.y - p * b23.y);
            }
        }
    }

    // Tail: n > 4 (~18.5%), chunks of 4 from the spill array.
    if (n > 4) {
        const u32x4* bkv =
            reinterpret_cast<const u32x4*>(bucketOv + (size_t)seq * 28); // 112B: 16B-aligned
        for (int i0 = 4; i0 < n; i0 += 4) {
            u32x4 t4 = bkv[(i0 - 4) >> 2];
            unsigned int r[4] = { t4.x, t4.y, t4.z, t4.w };
            float4 raw[4];
            #pragma unroll
            for (int j = 0; j < 4; ++j) {
                unsigned int g = (i0 + j < n) ? (r[j] & 0x7fffu) : 0u;
                raw[j] = T[(size_t)g * 4];
            }
            #pragma unroll
            for (int j = 0; j < 4; ++j) {
                float p = (float)(r[j] >> 15) * (1.0f / 131072.0f);
                const __half2* hp = reinterpret_cast<const __half2*>(&raw[j]);
                float2 a01 = __half22float2(hp[0]);
                float2 a23 = __half22float2(hp[1]);
                float2 b01 = __half22float2(hp[2]);
                float2 b23 = __half22float2(hp[3]);
                if (i0 + j < n) {
                    acc.x += EXP2F(a01.x - p * b01.x);
                    acc.y += EXP2F(a01.y - p * b01.y);
                    acc.z += EXP2F(a23.x - p * b23.x);
                    acc.w += EXP2F(a23.y - p * b23.y);
                }
            }
        }
    }

    // Out is written once and never re-read -> nontemporal (streaming: the
    // one place NT stores belong). 64B chunk per (seq,qg): full sectors.
    f32x4 o = { acc.x, acc.y, acc.z, acc.w };
    __builtin_nontemporal_store(o, (f32x4*)out + (size_t)seq * 32 + (qg << 2) + qw);
}

extern "C" void kernel_launch(void* const* d_in, const int* in_sizes, int n_in,
                              void* d_out, int out_size, void* d_ws, size_t ws_size,
                              hipStream_t stream) {
    const float* A    = (const float*)d_in[0];
    const float* B    = (const float*)d_in[1];
    const float* pos  = (const float*)d_in[2];
    const int*   gidx = (const int*)d_in[3];
    const int*   sidx = (const int*)d_in[4];
    float*       out  = (float*)d_out;

    // Workspace layout (256 MiB available, ~25.9 MB used):
    //   [0, 15,360,000)              AB16T: 8 x 30000 x 4 float4, qg-major
    //   [15,360,000, 15,680,000)     cnt: N_SEQS ints
    //   [15,680,000, 16,960,000)     bucket0: N_SEQS*4 uints (dense 16B rows)
    //   [16,960,000, 25,920,000)     bucketOv: N_SEQS*28 uints (spill)
    char*         ws       = (char*)d_ws;
    float4*       AB16     = (float4*)ws;
    int*          cnt      = (int*)(ws + (size_t)N_GENOMES * 32 * 16);
    unsigned int* bucket0  = (unsigned int*)(cnt + N_SEQS);
    unsigned int* bucketOv = bucket0 + (size_t)N_SEQS * 4;

    // Zero ONLY cnt (320 KB): bucket dead slots are masked by count in accum.
    hipMemsetAsync(cnt, 0, N_SEQS * sizeof(int), stream);

    prep_kernel<<<SCATTER_BLOCKS + COMPRESS_BLOCKS, 256, 0, stream>>>(
        A, B, pos, gidx, sidx, cnt, bucket0, bucketOv, AB16);

    // 8 qg-shards x 1250 seq-blocks; blockIdx%8 = qg -> XCD under
    // round-robin dispatch (bijective: 10000 % 8 == 0).
    accum_kernel<<<(N_SEQS / 64) * 8, 256, 0, stream>>>(
        AB16, cnt, bucket0, bucketOv, out);
}